// Round 10
// baseline (374.247 us; speedup 1.0000x reference)
//
#include <hip/hip_runtime.h>
#include <math.h>

// EntropicNeuralQuantileRegression on MI355X (gfx950) — MFMA v2.
// n=m=1024, F=64, R=8, H=128, EPS=0.1
//
//   A  = X @ W0[:64,:]            [1024,128] f32   (prep)
//   Bu = U @ W0[64:72,:] + b0     [1024,128] f32   (prep)
//   W1T/W2T = transposed bf16 weights [n][k]        (prep)
// Main: block = (8 i x 64 j); per round (1 i x 64 j):
//   h0 = sp(A[i]+Bu[j])  (VALU, Bu in regs, A from L1)  -> Ha bf16
//   h1 = sp(h0 @ W1 + b1)  mfma_f32_16x16x32_bf16, 4-wave N-split,
//        weight B-frags register-resident (launch_bounds(256,3))   -> Hb
//   h2 = sp(h1 @ W2 + b2)  -> Ha
//   phi = h2 @ Wout + bout; slack = Y.U - phi; per-WAVE 16-pair lse partial
//   (all-lane shuffle reduce, no LDS, no serial section).
// All f32->bf16 via v_cvt_pk_bf16_f32 (1 op / 2 elems).

typedef __attribute__((ext_vector_type(8))) short short8;
typedef __attribute__((ext_vector_type(4))) float f32x4;

__device__ __forceinline__ float softplus_f(float x) {
    return fmaxf(x, 0.0f) + __logf(1.0f + __expf(-fabsf(x)));
}

__device__ __forceinline__ unsigned int pk_bf16(float lo, float hi) {
    unsigned int r;
    asm("v_cvt_pk_bf16_f32 %0, %1, %2" : "=v"(r) : "v"(lo), "v"(hi));
    return r;
}

__device__ __forceinline__ unsigned short f2bf_prep(float x) {
    unsigned int u = __float_as_uint(x);
    u = (u + 0x7FFFu + ((u >> 16) & 1u)) >> 16;   // RNE (prep only, not hot)
    return (unsigned short)u;
}

__device__ __forceinline__ float bflo(unsigned int u) {
    return __uint_as_float(u << 16);
}
__device__ __forceinline__ float bfhi(unsigned int u) {
    return __uint_as_float(u & 0xFFFF0000u);
}

// ---------------- prep: A, Bu, transposed bf16 weights ----------------
__global__ __launch_bounds__(128) void prep_kernel(
    const float* __restrict__ X, const float* __restrict__ U,
    const float* __restrict__ W0, const float* __restrict__ b0,
    const float* __restrict__ W1, const float* __restrict__ W2,
    float* __restrict__ A, float* __restrict__ Bu,
    unsigned short* __restrict__ w1t, unsigned short* __restrict__ w2t)
{
    const int b = blockIdx.x, t = threadIdx.x;
    if (b < 1024) {                       // A row b: X[b,:64] @ W0[:64, t]
        const float* xr = X + b * 64;
        float s = 0.f;
        #pragma unroll 8
        for (int f = 0; f < 64; ++f) s += xr[f] * W0[f * 128 + t];
        A[b * 128 + t] = s;
    } else if (b < 2048) {                // Bu row j: U[j,:8] @ W0[64:72, t] + b0[t]
        const int j = b - 1024;
        const float* ur = U + j * 8;
        float s = b0[t];
        #pragma unroll
        for (int r = 0; r < 8; ++r) s += ur[r] * W0[(64 + r) * 128 + t];
        Bu[j * 128 + t] = s;
    } else if (b < 2176) {                // W1T[n][k] = bf16(W1[k][n])
        const int n = b - 2048;
        w1t[n * 128 + t] = f2bf_prep(W1[t * 128 + n]);
    } else {                              // W2T[n][k] = bf16(W2[k][n])
        const int n = b - 2176;
        w2t[n * 128 + t] = f2bf_prep(W2[t * 128 + n]);
    }
}

// ---------------- main ----------------
__global__ __launch_bounds__(256, 3) void main_kernel(
    const float* __restrict__ A, const float* __restrict__ Bu,
    const unsigned short* __restrict__ w1t, const unsigned short* __restrict__ w2t,
    const float* __restrict__ Y, const float* __restrict__ U,
    const float* __restrict__ b1, const float* __restrict__ b2,
    const float* __restrict__ Wout, const float* __restrict__ bout,
    float* __restrict__ part)
{
    __shared__ __align__(16) unsigned short Ha[64][136];   // 17 KB (16B-aligned rows)
    __shared__ __align__(16) unsigned short Hb[64][136];   // 17 KB

    const int tid  = threadIdx.x;
    const int lane = tid & 63;
    const int w    = tid >> 6;          // wave 0..3, owns out-cols [32w, 32w+32)
    const int ib   = blockIdx.x >> 4;   // 0..127
    const int jb   = blockIdx.x & 15;
    const int i0   = ib * 8;
    const int j0   = jb * 64;
    const int p    = tid >> 2;          // pair j_loc 0..63 (L0 / phi stages)
    const int q    = tid & 3;           // 32-feature quarter

    // ---- Bu slice (constant across rounds): 32 regs ----
    float bu_reg[32];
    {
        const float4* src = (const float4*)(Bu + (j0 + p) * 128 + q * 32);
        #pragma unroll
        for (int v = 0; v < 8; ++v) {
            float4 f = src[v];
            bu_reg[v * 4 + 0] = f.x; bu_reg[v * 4 + 1] = f.y;
            bu_reg[v * 4 + 2] = f.z; bu_reg[v * 4 + 3] = f.w;
        }
    }

    // ---- weight B-fragments, register-resident (64 VGPRs) ----
    short8 wf[2][2][4];     // [layer][n-tile][k-step]
    {
        const int col = lane & 15;
        const int kk  = (lane >> 4) * 8;
        #pragma unroll
        for (int nt = 0; nt < 2; ++nt)
            #pragma unroll
            for (int ks = 0; ks < 4; ++ks) {
                wf[0][nt][ks] = *(const short8*)(w1t + (w * 32 + nt * 16 + col) * 128 + ks * 32 + kk);
                wf[1][nt][ks] = *(const short8*)(w2t + (w * 32 + nt * 16 + col) * 128 + ks * 32 + kk);
            }
    }
    float rb1[2], rb2[2];
    rb1[0] = b1[w * 32 + (lane & 15)];      rb1[1] = b1[w * 32 + 16 + (lane & 15)];
    rb2[0] = b2[w * 32 + (lane & 15)];      rb2[1] = b2[w * 32 + 16 + (lane & 15)];
    const float bo = bout[0];

    #pragma unroll 1
    for (int rd = 0; rd < 8; ++rd) {
        const int i = i0 + rd;

        // ======== layer 0: h0 = sp(A[i] + Bu[j]) -> Ha ========
        {
            const float4* ag = (const float4*)(A + i * 128 + q * 32);
            unsigned int pk[16];
            #pragma unroll
            for (int v = 0; v < 8; ++v) {
                float4 av = ag[v];
                float f0 = softplus_f(av.x + bu_reg[v * 4 + 0]);
                float f1 = softplus_f(av.y + bu_reg[v * 4 + 1]);
                float f2 = softplus_f(av.z + bu_reg[v * 4 + 2]);
                float f3 = softplus_f(av.w + bu_reg[v * 4 + 3]);
                pk[v * 2 + 0] = pk_bf16(f0, f1);
                pk[v * 2 + 1] = pk_bf16(f2, f3);
            }
            uint4* dst = (uint4*)&Ha[p][q * 32];
            dst[0] = make_uint4(pk[0],  pk[1],  pk[2],  pk[3]);
            dst[1] = make_uint4(pk[4],  pk[5],  pk[6],  pk[7]);
            dst[2] = make_uint4(pk[8],  pk[9],  pk[10], pk[11]);
            dst[3] = make_uint4(pk[12], pk[13], pk[14], pk[15]);
        }
        __syncthreads();

        const int col = lane & 15, kk = (lane >> 4) * 8;
        const int crow = (lane >> 4) * 4;

        // ======== layer 1: Ha -> Hb ========
        {
            f32x4 acc[4][2];
            #pragma unroll
            for (int mt = 0; mt < 4; ++mt) {
                acc[mt][0] = (f32x4){rb1[0], rb1[0], rb1[0], rb1[0]};
                acc[mt][1] = (f32x4){rb1[1], rb1[1], rb1[1], rb1[1]};
            }
            #pragma unroll
            for (int ks = 0; ks < 4; ++ks) {
                short8 a[4];
                #pragma unroll
                for (int mt = 0; mt < 4; ++mt)
                    a[mt] = *(const short8*)&Ha[mt * 16 + col][ks * 32 + kk];
                #pragma unroll
                for (int mt = 0; mt < 4; ++mt) {
                    acc[mt][0] = __builtin_amdgcn_mfma_f32_16x16x32_bf16(a[mt], wf[0][0][ks], acc[mt][0], 0, 0, 0);
                    acc[mt][1] = __builtin_amdgcn_mfma_f32_16x16x32_bf16(a[mt], wf[0][1][ks], acc[mt][1], 0, 0, 0);
                }
            }
            #pragma unroll
            for (int mt = 0; mt < 4; ++mt)
                #pragma unroll
                for (int nt = 0; nt < 2; ++nt) {
                    unsigned int p01 = pk_bf16(softplus_f(acc[mt][nt][0]), softplus_f(acc[mt][nt][1]));
                    unsigned int p23 = pk_bf16(softplus_f(acc[mt][nt][2]), softplus_f(acc[mt][nt][3]));
                    const int r0 = mt * 16 + crow;
                    const int cc = w * 32 + nt * 16 + col;
                    Hb[r0 + 0][cc] = (unsigned short)p01;
                    Hb[r0 + 1][cc] = (unsigned short)(p01 >> 16);
                    Hb[r0 + 2][cc] = (unsigned short)p23;
                    Hb[r0 + 3][cc] = (unsigned short)(p23 >> 16);
                }
        }
        __syncthreads();

        // ======== layer 2: Hb -> Ha ========
        {
            f32x4 acc[4][2];
            #pragma unroll
            for (int mt = 0; mt < 4; ++mt) {
                acc[mt][0] = (f32x4){rb2[0], rb2[0], rb2[0], rb2[0]};
                acc[mt][1] = (f32x4){rb2[1], rb2[1], rb2[1], rb2[1]};
            }
            #pragma unroll
            for (int ks = 0; ks < 4; ++ks) {
                short8 a[4];
                #pragma unroll
                for (int mt = 0; mt < 4; ++mt)
                    a[mt] = *(const short8*)&Hb[mt * 16 + col][ks * 32 + kk];
                #pragma unroll
                for (int mt = 0; mt < 4; ++mt) {
                    acc[mt][0] = __builtin_amdgcn_mfma_f32_16x16x32_bf16(a[mt], wf[1][0][ks], acc[mt][0], 0, 0, 0);
                    acc[mt][1] = __builtin_amdgcn_mfma_f32_16x16x32_bf16(a[mt], wf[1][1][ks], acc[mt][1], 0, 0, 0);
                }
            }
            #pragma unroll
            for (int mt = 0; mt < 4; ++mt)
                #pragma unroll
                for (int nt = 0; nt < 2; ++nt) {
                    unsigned int p01 = pk_bf16(softplus_f(acc[mt][nt][0]), softplus_f(acc[mt][nt][1]));
                    unsigned int p23 = pk_bf16(softplus_f(acc[mt][nt][2]), softplus_f(acc[mt][nt][3]));
                    const int r0 = mt * 16 + crow;
                    const int cc = w * 32 + nt * 16 + col;
                    Ha[r0 + 0][cc] = (unsigned short)p01;
                    Ha[r0 + 1][cc] = (unsigned short)(p01 >> 16);
                    Ha[r0 + 2][cc] = (unsigned short)p23;
                    Ha[r0 + 3][cc] = (unsigned short)(p23 >> 16);
                }
        }
        __syncthreads();

        // ======== output layer + slack + per-wave lse ========
        {
            const uint4*  hp = (const uint4*)&Ha[p][q * 32];
            const float4* wo = (const float4*)(Wout + q * 32);
            float s = 0.f;
            #pragma unroll
            for (int v = 0; v < 4; ++v) {
                uint4  hh = hp[v];
                float4 w0 = wo[v * 2 + 0];
                float4 w1 = wo[v * 2 + 1];
                s += bflo(hh.x) * w0.x + bfhi(hh.x) * w0.y
                   + bflo(hh.y) * w0.z + bfhi(hh.y) * w0.w
                   + bflo(hh.z) * w1.x + bfhi(hh.z) * w1.y
                   + bflo(hh.w) * w1.z + bfhi(hh.w) * w1.w;
            }
            s += __shfl_xor(s, 1);
            s += __shfl_xor(s, 2);          // all 4 quad lanes hold full phi sum
            const float phi = s + bo;

            float4 u0 = *(const float4*)(U + (j0 + p) * 8);
            float4 u1 = *(const float4*)(U + (j0 + p) * 8 + 4);
            float4 y0 = *(const float4*)(Y + i * 8);
            float4 y1 = *(const float4*)(Y + i * 8 + 4);
            float cost = u0.x * y0.x + u0.y * y0.y + u0.z * y0.z + u0.w * y0.w
                       + u1.x * y1.x + u1.y * y1.y + u1.z * y1.z + u1.w * y1.w;
            const float v = cost - phi;     // slack, duplicated x4 per quad

            float m = v;
            m = fmaxf(m, __shfl_xor(m, 4));
            m = fmaxf(m, __shfl_xor(m, 8));
            m = fmaxf(m, __shfl_xor(m, 16));
            m = fmaxf(m, __shfl_xor(m, 32));
            float e = __expf((v - m) * 10.0f);
            e += __shfl_xor(e, 4);
            e += __shfl_xor(e, 8);
            e += __shfl_xor(e, 16);
            e += __shfl_xor(e, 32);
            if (lane == 0) {
                const int pi = i * 64 + jb * 4 + w;
                part[pi * 2 + 0] = m;
                part[pi * 2 + 1] = e * 0.25f;   // each pair counted 4x
            }
        }
        __syncthreads();     // out-stage Ha reads done before next L0 write
    }
}

// ---------------- combine: merge 64 chunk partials per row ----------------
__global__ __launch_bounds__(256) void combine_kernel(
    const float* __restrict__ part, float* __restrict__ out)
{
    const int i = blockIdx.x * 256 + threadIdx.x;
    if (i >= 1024) return;
    float M = -1e30f;
    for (int c = 0; c < 64; ++c) M = fmaxf(M, part[(i * 64 + c) * 2 + 0]);
    float S = 0.f;
    for (int c = 0; c < 64; ++c)
        S += part[(i * 64 + c) * 2 + 1] * __expf((part[(i * 64 + c) * 2 + 0] - M) * 10.0f);
    out[i] = M + 0.1f * (logf(S) - 6.9314718055994531f);   // log(1024)
}

extern "C" void kernel_launch(void* const* d_in, const int* in_sizes, int n_in,
                              void* d_out, int out_size, void* d_ws, size_t ws_size,
                              hipStream_t stream) {
    const float* X    = (const float*)d_in[0];
    const float* Y    = (const float*)d_in[1];
    const float* U    = (const float*)d_in[2];
    const float* W0   = (const float*)d_in[3];
    const float* b0   = (const float*)d_in[4];
    const float* W1   = (const float*)d_in[5];
    const float* b1   = (const float*)d_in[6];
    const float* W2   = (const float*)d_in[7];
    const float* b2   = (const float*)d_in[8];
    const float* Wout = (const float*)d_in[9];
    const float* bout = (const float*)d_in[10];
    float* out = (float*)d_out;

    char* ws = (char*)d_ws;
    float*          A    = (float*)(ws);                                      // 512 KB
    float*          Bu   = (float*)(ws + (512 << 10));                        // 512 KB
    unsigned short* w1t  = (unsigned short*)(ws + (1024 << 10));              // 32 KB
    unsigned short* w2t  = (unsigned short*)(ws + (1024 << 10) + (32 << 10)); // 32 KB
    float*          part = (float*)(ws + (1024 << 10) + (64 << 10));          // 512 KB

    prep_kernel<<<2304, 128, 0, stream>>>(X, U, W0, b0, W1, W2, A, Bu, w1t, w2t);
    main_kernel<<<2048, 256, 0, stream>>>(A, Bu, w1t, w2t, Y, U, b1, b2, Wout, bout, part);
    combine_kernel<<<4, 256, 0, stream>>>(part, out);
}